// Round 9
// baseline (124.459 us; speedup 1.0000x reference)
//
#include <hip/hip_runtime.h>
#include <math.h>

// TopKMoEGate: T = 16384, D = 1024, E = 64, topK = 2.
// Round 14: halve the DMA traffic (the real wall).
//  - R13 post-mortem: total global_load_lds bytes = 512 blk x 32 KB x 16
//    chunks = 268 MB; at the measured per-CU DMA path rate (~10 B/cy/CU,
//    = m13's HBM-copy share even for L2-resident data) that is 42 us --
//    exactly the measured duration. Kernel is DMA-traffic-bound; B image
//    re-read per block dominates (197 of 264 MB).
//  - Fix: 256 blocks (1/CU) x 512 thr x 64 tokens -> B traffic 98 MB,
//    total 165 MB -> ~26 us predicted at same path rate.
//  - 8 waves = (ts, es, kh); acc 32 VGPR; same verified image layout,
//    swizzle, conv8, C-mapping, butterfly epilogue.
//  - B ring-3 + x ring-3 (120 KB LDS): 2 compute-phases of latency cover
//    for both streams. Ledger: iter c issues [B_{c+2}(3), x_{c+2}(2)];
//    at wait(c) younger-than-B_c = x_{c+1}(2)+B_{c+1}(3) = 5 -> vmcnt(5)
//    for c<15, vmcnt(0) at c=15. Epilogue nz loads are always older ->
//    retired by first wait. Lsum overlays bs[1..2] (dead: chunks 13,14
//    finished before the c=15 barrier).

#define DDIM 1024
#define NEXP 64
#define NTOK 16384

typedef float f4 __attribute__((ext_vector_type(4)));
typedef short s8 __attribute__((ext_vector_type(8)));
typedef unsigned int u32;

static __device__ __forceinline__ void split3(float f, short& h, short& m, short& l) {
    const u32 uf = __float_as_uint(f);
    h = (short)(uf >> 16);
    const float r1 = f - __uint_as_float(uf & 0xffff0000u);
    const u32 u1 = __float_as_uint(r1);
    m = (short)(u1 >> 16);
    const float r2 = r1 - __uint_as_float(u1 & 0xffff0000u);
    l = (short)(__float_as_uint(r2) >> 16);
}

static __device__ __forceinline__ void gl_lds16(const void* g, void* l) {
    __builtin_amdgcn_global_load_lds(
        (const __attribute__((address_space(1))) u32*)g,
        (__attribute__((address_space(3))) u32*)l, 16, 0, 0);
}

// ---- kernel 0: slice gate_w into 3 bf16 levels, lane-ordered image ----
// unit16 U'(c,kk,lv,t,q,m) = c*1536 + (kk*3+lv)*256 + t*64 + q*16 + m,
// holding w[e=t*16+m][k0..k0+7], k0 = c*64 + kk*32 + q*8.  24 KB per chunk.
__global__ __launch_bounds__(256)
void w_prep(const float* __restrict__ gw, short* __restrict__ wimg) {
    const int uid = blockIdx.x * 256 + threadIdx.x;   // 8192 threads
    const int c   = uid >> 9;
    const int kk  = (uid >> 8) & 1;
    const int e   = (uid >> 2) & 63;
    const int q   = uid & 3;
    const int k0  = c * 64 + kk * 32 + q * 8;
    const float* src = gw + (size_t)e * DDIM + k0;
    s8 hv, mv, lv;
    #pragma unroll
    for (int j = 0; j < 8; ++j) {
        short h, m, l;
        split3(src[j], h, m, l);
        hv[j] = h; mv[j] = m; lv[j] = l;
    }
    const size_t base = (size_t)c * 1536 + (kk * 3) * 256
                      + (e >> 4) * 64 + q * 16 + (e & 15);
    *(s8*)(wimg + (base      ) * 8) = hv;
    *(s8*)(wimg + (base + 256) * 8) = mv;
    *(s8*)(wimg + (base + 512) * 8) = lv;
}

// pack hi 16 bits of (flo, fhi) -> u32 {lo16 = hi(flo), hi16 = hi(fhi)}
static __device__ __forceinline__ u32 packhi(float flo, float fhi) {
    return __builtin_amdgcn_perm(__float_as_uint(fhi), __float_as_uint(flo),
                                 0x07060302u);
}

union FragU { u32 u[4]; s8 v; };

// convert 8 consecutive floats -> 3-level bf16 frags (h, m, l)  [r8-verified]
static __device__ __forceinline__ void conv8(const float* f, s8& h, s8& m, s8& l) {
    FragU H, M, L;
    #pragma unroll
    for (int j = 0; j < 4; ++j) {
        const float f0 = f[2 * j], f1 = f[2 * j + 1];
        H.u[j] = packhi(f0, f1);
        const float g0 = f0 - __uint_as_float(__float_as_uint(f0) & 0xffff0000u);
        const float g1 = f1 - __uint_as_float(__float_as_uint(f1) & 0xffff0000u);
        M.u[j] = packhi(g0, g1);
        const float e0 = g0 - __uint_as_float(__float_as_uint(g0) & 0xffff0000u);
        const float e1 = g1 - __uint_as_float(__float_as_uint(g1) & 0xffff0000u);
        L.u[j] = packhi(e0, e1);
    }
    h = H.v; m = M.v; l = L.v;
}

#define MF(A, B, C) __builtin_amdgcn_mfma_f32_16x16x32_bf16((A), (B), (C), 0, 0, 0)

// ---- kernel 1: fused GEMM + noisy top-2 + sparse softmax ----
__global__ __launch_bounds__(512, 1)
void gate_fused(const float* __restrict__ x,
                const short* __restrict__ wimg,
                const float* __restrict__ noise_weight,
                const float* __restrict__ noise,
                float* __restrict__ out_w,
                float* __restrict__ out_i)
{
    __shared__ short bs[3][1536 * 8];           // B ring-3: 3 x 24 KB
    __shared__ float xs[3][64 * 64];            // x ring-3: 3 x 16 KB (swizzled)

    const int tid  = threadIdx.x;
    const int lane = tid & 63;
    const int wv   = tid >> 6;                  // 0..7
    const int ts   = wv >> 2;                   // token half (32 tokens)
    const int es   = (wv >> 1) & 1;             // expert half (2 t-tiles)
    const int kh   = wv & 1;                    // k32 half of each chunk
    const int m    = lane & 15;
    const int q    = lane >> 4;
    const int tokBase = blockIdx.x * 64;

    // epilogue operands FIRST (oldest in vmcnt order; retired by first wait)
    const float nw = noise_weight[lane];
    float nz[8];
    #pragma unroll
    for (int tt = 0; tt < 8; ++tt)
        nz[tt] = noise[(size_t)(tokBase + wv * 8 + tt) * NEXP + lane];

    f4 acc0[2][2], acc1[2][2];                  // [mt][tt]
    #pragma unroll
    for (int a = 0; a < 2; ++a)
        #pragma unroll
        for (int b = 0; b < 2; ++b) { acc0[a][b] = (f4)0.f; acc1[a][b] = (f4)0.f; }

    // B: 24 ops/chunk -> 3 per wave
#define STAGE_B(BUF, C) {                                                  \
    const short* _c = wimg + (size_t)(C) * 12288;                          \
    _Pragma("unroll")                                                      \
    for (int _i = 0; _i < 3; ++_i) {                                       \
        const int _off = (wv * 3 + _i) * 512;                              \
        gl_lds16(_c + _off + lane * 8, &bs[BUF][_off]);                    \
    } }

    // x: 64 tok x 64 floats = 16 ops/chunk -> 2 per wave, quad-swizzled src
#define STAGE_X(BUF, C) {                                                  \
    _Pragma("unroll")                                                      \
    for (int _j = 0; _j < 2; ++_j) {                                       \
        const int _qi = (wv * 2 + _j) * 64 + lane;                         \
        const int _tk = _qi >> 4;                                          \
        const int _qd = (_qi & 15) ^ (_tk & 15);                           \
        gl_lds16(x + (size_t)(tokBase + _tk) * DDIM + (C) * 64 + _qd * 4,  \
                 &xs[BUF][(wv * 2 + _j) * 256]);                           \
    } }

    // consume chunk: wave (ts,es,kh), 2 mt x 2 tt x 6 MFMA (verified maps)
#define COMPUTE(BUF, XBUF) {                                               \
    s8 ah[2], am_[2], al[2];                                               \
    _Pragma("unroll")                                                      \
    for (int mt = 0; mt < 2; ++mt) {                                       \
        const int tok = ts * 32 + mt * 16 + m;                             \
        const int qd0 = kh * 8 + q * 2;                                    \
        const int sq0 = qd0 ^ (tok & 15);                                  \
        const int sq1 = (qd0 + 1) ^ (tok & 15);                            \
        const f4 xa = *(const f4*)&xs[XBUF][tok * 64 + sq0 * 4];           \
        const f4 xb = *(const f4*)&xs[XBUF][tok * 64 + sq1 * 4];           \
        float xf[8];                                                       \
        _Pragma("unroll")                                                  \
        for (int i = 0; i < 4; ++i) { xf[i] = xa[i]; xf[4 + i] = xb[i]; }  \
        conv8(xf, ah[mt], am_[mt], al[mt]);                                \
    }                                                                      \
    _Pragma("unroll")                                                      \
    for (int tt = 0; tt < 2; ++tt) {                                       \
        const int p = (kh * 3) * 256 + (es * 2 + tt) * 64 + lane;          \
        const s8 bh = *(const s8*)&bs[BUF][(p      ) * 8];                 \
        const s8 bm = *(const s8*)&bs[BUF][(p + 256) * 8];                 \
        const s8 bl = *(const s8*)&bs[BUF][(p + 512) * 8];                 \
        _Pragma("unroll")                                                  \
        for (int mt = 0; mt < 2; ++mt) {                                   \
            acc0[mt][tt] = MF(ah[mt],  bh, acc0[mt][tt]);                  \
            acc1[mt][tt] = MF(ah[mt],  bm, acc1[mt][tt]);                  \
            acc1[mt][tt] = MF(am_[mt], bh, acc1[mt][tt]);                  \
            acc1[mt][tt] = MF(ah[mt],  bl, acc1[mt][tt]);                  \
            acc1[mt][tt] = MF(am_[mt], bm, acc1[mt][tt]);                  \
            acc1[mt][tt] = MF(al[mt],  bh, acc1[mt][tt]);                  \
        }                                                                  \
    } }

    // prologue FIFO: [B0(3), x0(2), B1(3), x1(2)]  (after nz/nw, older)
    STAGE_B(0, 0);
    STAGE_X(0, 0);
    STAGE_B(1, 1);
    STAGE_X(1, 1);

    #pragma unroll
    for (int c = 0; c < 16; ++c) {
        // need B_c,x_c retired; younger = x_{c+1}(2)+B_{c+1}(3) = 5
        if (c < 15) {
            asm volatile("s_waitcnt vmcnt(5)" ::: "memory");
        } else {
            asm volatile("s_waitcnt vmcnt(0) lgkmcnt(0)" ::: "memory");
        }
        __builtin_amdgcn_sched_barrier(0);
        __builtin_amdgcn_s_barrier();           // raw: no vmcnt(0) drain
        if (c + 2 < 16) {
            STAGE_B((c + 2) % 3, c + 2);
            STAGE_X((c + 2) % 3, c + 2);
        }
        __builtin_amdgcn_sched_barrier(0);      // pin stage before compute
        COMPUTE(c % 3, c % 3);
    }

    // K-half partials -> LDS overlay on bs[1..2] (chunks 13,14: all waves
    // finished them before the c=15 barrier; chunk 15 uses bs[0] - untouched).
    float (*Lsum)[64][68] = reinterpret_cast<float(*)[64][68]>(&bs[1][0]);
    #pragma unroll
    for (int mt = 0; mt < 2; ++mt)
        #pragma unroll
        for (int tt = 0; tt < 2; ++tt)
            #pragma unroll
            for (int r = 0; r < 4; ++r)
                Lsum[kh][ts * 32 + mt * 16 + q * 4 + r][(es * 2 + tt) * 16 + m]
                    = acc0[mt][tt][r] + acc1[mt][tt][r];
    __syncthreads();

    // wave wv handles tokens wv*8 .. wv*8+7; lane = expert (r3-verified)
    #pragma unroll
    for (int tt = 0; tt < 8; ++tt) {
        const int tok  = wv * 8 + tt;
        const int gtok = tokBase + tok;
        const float ln = fmaf(nz[tt], nw,
                              Lsum[0][tok][lane] + Lsum[1][tok][lane]);

        float v1 = ln; int i1 = lane;
        #pragma unroll
        for (int off = 32; off > 0; off >>= 1) {
            const float vo = __shfl_xor(v1, off, 64);
            const int   io = __shfl_xor(i1, off, 64);
            if (vo > v1 || (vo == v1 && io < i1)) { v1 = vo; i1 = io; }
        }
        float v2 = (lane == i1) ? -3.4e38f : ln; int i2 = lane;
        #pragma unroll
        for (int off = 32; off > 0; off >>= 1) {
            const float vo = __shfl_xor(v2, off, 64);
            const int   io = __shfl_xor(i2, off, 64);
            if (vo > v2 || (vo == v2 && io < i2)) { v2 = vo; i2 = io; }
        }

        const float d   = expf(v2 - v1);
        const float inv = 1.f / (1.f + d);
        const float wgt = (lane == i1) ? inv : ((lane == i2) ? d * inv : 0.f);
        out_w[(size_t)gtok * NEXP + lane] = wgt;
        if (lane == 0) {
            out_i[(size_t)gtok * 2]     = (float)i1;
            out_i[(size_t)gtok * 2 + 1] = (float)i2;
        }
    }
}

extern "C" void kernel_launch(void* const* d_in, const int* in_sizes, int n_in,
                              void* d_out, int out_size, void* d_ws, size_t ws_size,
                              hipStream_t stream) {
    const float* x     = (const float*)d_in[0];
    const float* gw    = (const float*)d_in[1];
    const float* nwt   = (const float*)d_in[2];
    const float* noise = (const float*)d_in[3];
    float* out_w = (float*)d_out;                        // [NTOK][64]
    float* out_i = (float*)d_out + (size_t)NTOK * NEXP;  // [NTOK][2] as float

    short* wimg = (short*)d_ws;                          // 384 KB image

    hipLaunchKernelGGL(w_prep, dim3(32), dim3(256), 0, stream, gw, wimg);
    hipLaunchKernelGGL(gate_fused, dim3(NTOK / 64), dim3(512), 0, stream,
                       x, wimg, nwt, noise, out_w, out_i);
}